// Round 5
// baseline (454.235 us; speedup 1.0000x reference)
//
#include <hip/hip_runtime.h>
#include <hip/hip_bf16.h>
#include <stdint.h>

#define H 128
#define NNODES 100000
#define NEDGE 500000
#define GEMM_GRID 1024
#define TILE_ROWS 16
#define NTILES (2 * (NNODES / TILE_ROWS))  // 12500, z-interleaved

// ws layout:
//   [0, 65536)        : Bsw  bf16, fragment-swizzled w1 (16 kb-groups x 256 cols x 8)
//   [65536, +25.6MB)x4: T_ps, T_pd, T_os, T_od  bf16 [100000][128]
#define BSW_BYTES 65536
#define TBL_ELEMS (NNODES * H)
#define WS_NEEDED ((size_t)BSW_BYTES + 4ULL * TBL_ELEMS * 2ULL)

typedef __bf16 bf16x8 __attribute__((ext_vector_type(8)));
typedef float f32x4 __attribute__((ext_vector_type(4)));

union frag_cast { uint4 u; bf16x8 b; ushort s[8]; };

__device__ __forceinline__ ushort f2bf(float f) {
    __hip_bfloat16 h = __float2bfloat16(f);
    return *(ushort*)&h;
}

__device__ __forceinline__ void bf2_to_f(uint32_t u, float& lo, float& hi) {
    union { uint32_t i; float f; } a, b;
    a.i = u << 16;
    b.i = u & 0xffff0000u;
    lo = a.f;
    hi = b.f;
}

// Build fragment-swizzled bf16 B from w1.
// Bsw element i: j=i&7, n=(i>>3)&255, kb=i>>11; k=kb*8+j;
// B[k][n] = (n<128) ? w1[k][n] : w1[128+k][n-128]
__global__ __launch_bounds__(256) void prep_bsw(const float* __restrict__ w1,
                                                ushort* __restrict__ bsw) {
    int i = blockIdx.x * 256 + threadIdx.x;  // 0..32767
    int j = i & 7;
    int n = (i >> 3) & 255;
    int kb = i >> 11;
    int k = kb * 8 + j;
    int r = (n < 128) ? k : (128 + k);
    int c = n & 127;
    bsw[i] = f2bf(w1[r * H + c]);
}

// Waveful GEMM: each WAVE independently computes one [16 rows x 256 cols] tile.
// No LDS, no barriers. A: 16 contiguous rows (8 KB streaming region), loaded
// global->VGPR->bf16, zero redundancy. B: 64 KB bsw, refetched per s-step from
// L1/L2, latency hidden under MFMA. acc[16] spans all 256 cols so the wave
// writes COMPLETE 256-B rows of both destination tables.
__global__ __launch_bounds__(256, 3) void gemm_tables(
    const float* __restrict__ zp, const float* __restrict__ zo,
    const ushort* __restrict__ bsw, const float* __restrict__ b1,
    ushort* __restrict__ t_ps, ushort* __restrict__ t_pd,
    ushort* __restrict__ t_os, ushort* __restrict__ t_od) {
    const int t = threadIdx.x;
    const int wave = t >> 6;
    const int lane = t & 63;
    const int l15 = lane & 15;
    const int quad = lane >> 4;

    const int wid = blockIdx.x * 4 + wave;
    const int nw = gridDim.x * 4;

    // bias for cols >= 128 (nt 8..15): b1[(nt-8)*16 + l15]
    float bias[8];
#pragma unroll
    for (int i = 0; i < 8; ++i) bias[i] = b1[i * 16 + l15];

    for (int tile = wid; tile < NTILES; tile += nw) {
        const int zsel = tile & 1;
        const int node0 = (tile >> 1) * TILE_ROWS;
        const float* __restrict__ zrow =
            (zsel ? zo : zp) + (size_t)node0 * H;

        f32x4 acc[16];
#pragma unroll
        for (int nt = 0; nt < 16; ++nt) acc[nt] = (f32x4){0.f, 0.f, 0.f, 0.f};

#pragma unroll
        for (int s = 0; s < 4; ++s) {
            // A fragment: row = l15, k = s*32 + quad*8 + j  (contiguous 32 B)
            const float* p = zrow + (size_t)l15 * H + s * 32 + quad * 8;
            const float4 v0 = *(const float4*)p;
            const float4 v1 = *(const float4*)(p + 4);
            frag_cast a;
            a.s[0] = f2bf(v0.x); a.s[1] = f2bf(v0.y);
            a.s[2] = f2bf(v0.z); a.s[3] = f2bf(v0.w);
            a.s[4] = f2bf(v1.x); a.s[5] = f2bf(v1.y);
            a.s[6] = f2bf(v1.z); a.s[7] = f2bf(v1.w);

            const ushort* brow = bsw + (size_t)(s * 4 + quad) * 256 * 8 + l15 * 8;
#pragma unroll
            for (int nt = 0; nt < 16; ++nt) {
                frag_cast b;
                b.u = *(const uint4*)(brow + nt * 16 * 8);
                acc[nt] = __builtin_amdgcn_mfma_f32_16x16x32_bf16(
                    a.b, b.b, acc[nt], 0, 0, 0);
            }
        }

        // Epilogue: D col=l15 (within nt group), row = quad*4 + r.
        ushort* __restrict__ stab = zsel ? t_os : t_ps;
        ushort* __restrict__ dtab = zsel ? t_od : t_pd;
#pragma unroll
        for (int nt = 0; nt < 16; ++nt) {
            const int col = nt * 16 + l15;
            ushort* __restrict__ dst = (nt < 8) ? stab : dtab;
            const int c = col & 127;
            const float bb = (nt < 8) ? 0.f : bias[nt - 8];
#pragma unroll
            for (int r = 0; r < 4; ++r) {
                const int grow = node0 + quad * 4 + r;
                dst[(size_t)grow * H + c] = f2bf(acc[nt][r] + bb);
            }
        }
    }
}

// 16 lanes per group; each group handles 4 consecutive edges (4x MLP).
// Each lane covers 8 channels via 16B bf16 loads.
__global__ __launch_bounds__(256) void edge_kernel(
    const __hip_bfloat16* __restrict__ t_ps, const __hip_bfloat16* __restrict__ t_pd,
    const __hip_bfloat16* __restrict__ t_os, const __hip_bfloat16* __restrict__ t_od,
    const int* __restrict__ ptnp, const int* __restrict__ nptp,
    const int* __restrict__ nptnp,
    const float* __restrict__ w2, const float* __restrict__ b2,
    float* __restrict__ out) {
    const int tid = blockIdx.x * 256 + threadIdx.x;
    const int gg = tid >> 4;       // group id, 0..374999
    if (gg >= (3 * NEDGE) / 4) return;
    const int lane = tid & 15;
    const int e0 = gg * 4;         // 4 edges, never straddle a type boundary

    const __hip_bfloat16 *src_tbl, *dst_tbl;
    const int* idx;
    int ebase;
    if (e0 < NEDGE) {
        idx = ptnp; ebase = e0;
        src_tbl = t_ps; dst_tbl = t_od;
    } else if (e0 < 2 * NEDGE) {
        idx = nptp; ebase = e0 - NEDGE;
        src_tbl = t_os; dst_tbl = t_pd;
    } else {
        idx = nptnp; ebase = e0 - 2 * NEDGE;
        src_tbl = t_os; dst_tbl = t_od;
    }

    const int4 si = *(const int4*)(idx + ebase);
    const int4 di = *(const int4*)(idx + NEDGE + ebase);

    // Issue all 8 gathers up front (independent -> 8 in flight per lane).
    const uint4 s0 = *(const uint4*)(src_tbl + (size_t)si.x * H + lane * 8);
    const uint4 d0 = *(const uint4*)(dst_tbl + (size_t)di.x * H + lane * 8);
    const uint4 s1 = *(const uint4*)(src_tbl + (size_t)si.y * H + lane * 8);
    const uint4 d1 = *(const uint4*)(dst_tbl + (size_t)di.y * H + lane * 8);
    const uint4 s2 = *(const uint4*)(src_tbl + (size_t)si.z * H + lane * 8);
    const uint4 d2 = *(const uint4*)(dst_tbl + (size_t)di.z * H + lane * 8);
    const uint4 s3 = *(const uint4*)(src_tbl + (size_t)si.w * H + lane * 8);
    const uint4 d3 = *(const uint4*)(dst_tbl + (size_t)di.w * H + lane * 8);

    const float4 w2a = *(const float4*)(w2 + lane * 8);
    const float4 w2b = *(const float4*)(w2 + lane * 8 + 4);
    const float wv[8] = {w2a.x, w2a.y, w2a.z, w2a.w, w2b.x, w2b.y, w2b.z, w2b.w};

    float sum[4] = {0.f, 0.f, 0.f, 0.f};
    const uint4* sv[4] = {&s0, &s1, &s2, &s3};
    const uint4* dv[4] = {&d0, &d1, &d2, &d3};
#pragma unroll
    for (int e = 0; e < 4; ++e) {
        const uint32_t* su = (const uint32_t*)sv[e];
        const uint32_t* du = (const uint32_t*)dv[e];
        float acc = 0.f;
#pragma unroll
        for (int q = 0; q < 4; ++q) {
            float a0, a1, b0, b1v;
            bf2_to_f(su[q], a0, a1);
            bf2_to_f(du[q], b0, b1v);
            acc = fmaf(fmaxf(a0 + b0, 0.f), wv[2 * q], acc);
            acc = fmaf(fmaxf(a1 + b1v, 0.f), wv[2 * q + 1], acc);
        }
        sum[e] = acc;
    }

#pragma unroll
    for (int e = 0; e < 4; ++e) {
        sum[e] += __shfl_down(sum[e], 8, 16);
        sum[e] += __shfl_down(sum[e], 4, 16);
        sum[e] += __shfl_down(sum[e], 2, 16);
        sum[e] += __shfl_down(sum[e], 1, 16);
    }
    if (lane == 0) {
        const float bb = b2[0];
        float4 o = {sum[0] + bb, sum[1] + bb, sum[2] + bb, sum[3] + bb};
        *(float4*)(out + e0) = o;
    }
}

// Fallback (only if ws_size is too small): direct per-edge compute, fp32.
__global__ __launch_bounds__(128) void edge_direct(
    const float* __restrict__ zp, const float* __restrict__ zo,
    const int* __restrict__ ptnp, const int* __restrict__ nptp,
    const int* __restrict__ nptnp,
    const float* __restrict__ w1, const float* __restrict__ b1,
    const float* __restrict__ w2, const float* __restrict__ b2,
    float* __restrict__ out) {
    const int g = blockIdx.x;
    const int j = threadIdx.x;

    const float *src, *dst;
    int si, di;
    if (g < NEDGE) {
        si = ptnp[g]; di = ptnp[NEDGE + g]; src = zp; dst = zo;
    } else if (g < 2 * NEDGE) {
        const int e = g - NEDGE;
        si = nptp[e]; di = nptp[NEDGE + e]; src = zo; dst = zp;
    } else {
        const int e = g - 2 * NEDGE;
        si = nptnp[e]; di = nptnp[NEDGE + e]; src = zo; dst = zo;
    }
    const float* zs = src + si * H;
    const float* zd = dst + di * H;

    float acc = b1[j];
    for (int k = 0; k < H; ++k) acc = fmaf(zs[k], w1[k * H + j], acc);
    for (int k = 0; k < H; ++k) acc = fmaf(zd[k], w1[(H + k) * H + j], acc);
    float v = fmaxf(acc, 0.f) * w2[j];

    for (int off = 32; off > 0; off >>= 1) v += __shfl_down(v, off, 64);
    __shared__ float parts[2];
    if ((j & 63) == 0) parts[j >> 6] = v;
    __syncthreads();
    if (j == 0) out[g] = parts[0] + parts[1] + b2[0];
}

extern "C" void kernel_launch(void* const* d_in, const int* in_sizes, int n_in,
                              void* d_out, int out_size, void* d_ws, size_t ws_size,
                              hipStream_t stream) {
    const float* zp    = (const float*)d_in[0];
    const float* zo    = (const float*)d_in[1];
    const int*   ptnp  = (const int*)d_in[2];
    const int*   nptp  = (const int*)d_in[3];
    const int*   nptnp = (const int*)d_in[4];
    const float* w1    = (const float*)d_in[5];
    const float* b1    = (const float*)d_in[6];
    const float* w2    = (const float*)d_in[7];
    const float* b2    = (const float*)d_in[8];
    float* out = (float*)d_out;

    if (ws_size < WS_NEEDED) {
        edge_direct<<<3 * NEDGE, 128, 0, stream>>>(zp, zo, ptnp, nptp, nptnp,
                                                   w1, b1, w2, b2, out);
        return;
    }

    char* ws = (char*)d_ws;
    ushort* bsw = (ushort*)ws;
    ushort* t_ps = (ushort*)(ws + BSW_BYTES);
    ushort* t_pd = t_ps + TBL_ELEMS;
    ushort* t_os = t_pd + TBL_ELEMS;
    ushort* t_od = t_os + TBL_ELEMS;

    prep_bsw<<<128, 256, 0, stream>>>(w1, bsw);

    gemm_tables<<<GEMM_GRID, 256, 0, stream>>>(
        zp, zo, bsw, b1, t_ps, t_pd, t_os, t_od);

    const int ngroups = (3 * NEDGE) / 4;                 // 375000
    const int nblocks = (ngroups * 16 + 255) / 256;      // 23438
    edge_kernel<<<nblocks, 256, 0, stream>>>(
        (const __hip_bfloat16*)t_ps, (const __hip_bfloat16*)t_pd,
        (const __hip_bfloat16*)t_os, (const __hip_bfloat16*)t_od,
        ptnp, nptp, nptnp, w2, b2, out);
}

// Round 6
// 266.065 us; speedup vs baseline: 1.7072x; 1.7072x over previous
//
#include <hip/hip_runtime.h>
#include <hip/hip_bf16.h>
#include <stdint.h>

#define H 128
#define NNODES 100000
#define NEDGE 500000
#define MT 32                  // node rows per GEMM tile (100000 = 3125*32 exact)
#define NT2 6250               // tiles across both z inputs (z-interleaved)
#define GEMM_GRID 768          // 3 blocks/CU (LDS-limited)
#define EPI_S 266              // ebuf stride in ushorts (256 + 10 pad)

// ws layout:
//   [0, 65536)        : Bsw  bf16, fragment-swizzled w1 (16 kb-groups x 256 cols x 8)
//   [65536, +25.6MB)x4: T_ps, T_pd, T_os, T_od  bf16 [100000][128]
#define BSW_BYTES 65536
#define TBL_ELEMS (NNODES * H)
#define WS_NEEDED ((size_t)BSW_BYTES + 4ULL * TBL_ELEMS * 2ULL)

typedef __bf16 bf16x8 __attribute__((ext_vector_type(8)));
typedef float f32x4 __attribute__((ext_vector_type(4)));

union frag_cast { uint4 u; bf16x8 b; ushort s[8]; };

__device__ __forceinline__ ushort f2bf(float f) {
    __hip_bfloat16 h = __float2bfloat16(f);
    return *(ushort*)&h;
}

__device__ __forceinline__ void bf2_to_f(uint32_t u, float& lo, float& hi) {
    union { uint32_t i; float f; } a, b;
    a.i = u << 16;
    b.i = u & 0xffff0000u;
    lo = a.f;
    hi = b.f;
}

// Build fragment-swizzled bf16 B from w1.
// Bsw element i: j=i&7, n=(i>>3)&255, kb=i>>11; k=kb*8+j;
// B[k][n] = (n<128) ? w1[k][n] : w1[128+k][n-128]
__global__ __launch_bounds__(256) void prep_bsw(const float* __restrict__ w1,
                                                ushort* __restrict__ bsw) {
    int i = blockIdx.x * 256 + threadIdx.x;  // 0..32767
    int j = i & 7;
    int n = (i >> 3) & 255;
    int kb = i >> 11;
    int k = kb * 8 + j;
    int r = (n < 128) ? k : (128 + k);
    int c = n & 127;
    bsw[i] = f2bf(w1[r * H + c]);
}

// Persistent GEMM, 256 thr = 4 waves, tile = [32 rows x 256 cols].
// A: global_load_lds dwordx4 into double-buffered LDS (XOR source swizzle);
// DMA for tile t+1 issued right after the top barrier, hidden behind
// compute+epilogue (2 barriers/tile total). Epilogue goes through a padded
// LDS buffer so global stores are full-line coalesced uint4 (each wave
// writes 4 KB contiguous) -- kills the 3x write amplification measured in r5.
__global__ __launch_bounds__(256, 3) void gemm_tables(
    const float* __restrict__ zp, const float* __restrict__ zo,
    const ushort* __restrict__ bsw, const float* __restrict__ b1,
    ushort* __restrict__ t_ps, ushort* __restrict__ t_pd,
    ushort* __restrict__ t_os, ushort* __restrict__ t_od) {
    __shared__ float abuf[2][MT * H];     // 2 x 16 KB A staging
    __shared__ ushort ebuf[MT * EPI_S];   // 17 KB epilogue staging

    const int t = threadIdx.x;
    const int wave = t >> 6;
    const int lane = t & 63;
    const int l15 = lane & 15;
    const int quad = lane >> 4;
    const int n0 = wave * 64;            // wave's output col base (0..255)
    const int half = wave >> 1;          // 0: s-cols, 1: d-cols

    // ---- Per-block constants: B fragments (16 x 16B, L2-hot) + bias ----
    frag_cast bfr[4][4];
#pragma unroll
    for (int s = 0; s < 4; ++s)
#pragma unroll
        for (int nt = 0; nt < 4; ++nt)
            bfr[s][nt].u = *(const uint4*)(bsw + ((s * 4 + quad) * 256 + n0 + nt * 16 + l15) * 8);

    float bias[4] = {0.f, 0.f, 0.f, 0.f};
    if (half) {
#pragma unroll
        for (int nt = 0; nt < 4; ++nt)
            bias[nt] = b1[(n0 - 128) + nt * 16 + l15];
    }

    // Staging offsets (constant across tiles):
    // iter i: LDS linear = (wave*4+i)*1024B + lane*16B -> row r=(wave*4+i)*2+(lane>>5),
    // chunk j=lane&31; source chunk = j ^ (r&15)  (so compute reads (2c)^l15).
    int src_off[4], lds_off[4];
#pragma unroll
    for (int i = 0; i < 4; ++i) {
        const int r = (wave * 4 + i) * 2 + (lane >> 5);
        const int jsrc = (lane & 31) ^ (r & 15);
        src_off[i] = r * H + jsrc * 4;      // floats
        lds_off[i] = (wave * 4 + i) * 256;  // floats
    }

    // ---- Prologue: DMA first tile into buf 0 ----
    int tile = blockIdx.x;
    if (tile < NT2) {
        const float* zt = ((tile & 1) ? zo : zp) + (size_t)((tile >> 1) * MT) * H;
#pragma unroll
        for (int i = 0; i < 4; ++i)
            __builtin_amdgcn_global_load_lds(
                (const __attribute__((address_space(1))) uint32_t*)(zt + src_off[i]),
                (__attribute__((address_space(3))) uint32_t*)(&abuf[0][0] + lds_off[i]),
                16, 0, 0);
    }

    int buf = 0;
    for (; tile < NT2; tile += GEMM_GRID) {
        __syncthreads();  // B_top: drains DMA(tile); also fences ebuf reuse

        // ---- Prefetch DMA for next tile into the other buffer ----
        const int nxt = tile + GEMM_GRID;
        if (nxt < NT2) {
            const float* zt = ((nxt & 1) ? zo : zp) + (size_t)((nxt >> 1) * MT) * H;
#pragma unroll
            for (int i = 0; i < 4; ++i)
                __builtin_amdgcn_global_load_lds(
                    (const __attribute__((address_space(1))) uint32_t*)(zt + src_off[i]),
                    (__attribute__((address_space(3))) uint32_t*)(&abuf[buf ^ 1][0] + lds_off[i]),
                    16, 0, 0);
        }

        // ---- Compute: rows 0..31 (2 mt), wave cols n0..n0+63 (4 nt), K=128 ----
        const float* __restrict__ ab = &abuf[buf][0];
        f32x4 acc[2][4];
#pragma unroll
        for (int mt = 0; mt < 2; ++mt)
#pragma unroll
            for (int nt = 0; nt < 4; ++nt)
                acc[mt][nt] = (f32x4){0.f, 0.f, 0.f, 0.f};

#pragma unroll
        for (int s = 0; s < 4; ++s)
#pragma unroll
            for (int mt = 0; mt < 2; ++mt) {
                const int row = mt * 16 + l15;
                const int c = s * 4 + quad;  // 32B chunk -> b128 units 2c, 2c+1
                const float4 vlo = *(const float4*)(ab + row * H + ((2 * c) ^ l15) * 4);
                const float4 vhi = *(const float4*)(ab + row * H + ((2 * c + 1) ^ l15) * 4);
                frag_cast a;
                a.s[0] = f2bf(vlo.x); a.s[1] = f2bf(vlo.y);
                a.s[2] = f2bf(vlo.z); a.s[3] = f2bf(vlo.w);
                a.s[4] = f2bf(vhi.x); a.s[5] = f2bf(vhi.y);
                a.s[6] = f2bf(vhi.z); a.s[7] = f2bf(vhi.w);
#pragma unroll
                for (int nt = 0; nt < 4; ++nt)
                    acc[mt][nt] = __builtin_amdgcn_mfma_f32_16x16x32_bf16(
                        a.b, bfr[s][nt].b, acc[mt][nt], 0, 0, 0);
            }

        // ---- Epilogue stage: acc -> ebuf (D: col=l15, row=quad*4+reg) ----
#pragma unroll
        for (int mt = 0; mt < 2; ++mt)
#pragma unroll
            for (int nt = 0; nt < 4; ++nt) {
                const int col = n0 + nt * 16 + l15;
#pragma unroll
                for (int r = 0; r < 4; ++r)
                    ebuf[(mt * 16 + quad * 4 + r) * EPI_S + col] =
                        f2bf(acc[mt][nt][r] + bias[nt]);
            }

        __syncthreads();  // B_mid: ebuf ready (DMA covered by compute+epi)

        // ---- Coalesced stores: 1024 chunks of 16B; wave writes 4 KB contig ----
        const int zsel = tile & 1;
        const int node0 = (tile >> 1) * MT;
        ushort* __restrict__ stab = zsel ? t_os : t_ps;
        ushort* __restrict__ dtab = zsel ? t_od : t_pd;
#pragma unroll
        for (int i = 0; i < 4; ++i) {
            const int c = i * 256 + t;        // 0..1023
            const int table = c >> 9;         // 0: s-table, 1: d-table
            const int row = (c >> 4) & 31;
            const int ch = c & 15;            // 16B chunk within row
            ushort* __restrict__ dst = table ? dtab : stab;
            *(uint4*)(dst + (size_t)(node0 + row) * H + ch * 8) =
                *(const uint4*)(ebuf + row * EPI_S + table * 128 + ch * 8);
        }

        buf ^= 1;
    }
}

// 16 lanes per edge; each lane handles 8 channels (16B bf16 loads).
__global__ __launch_bounds__(256) void edge_kernel(
    const __hip_bfloat16* __restrict__ t_ps, const __hip_bfloat16* __restrict__ t_pd,
    const __hip_bfloat16* __restrict__ t_os, const __hip_bfloat16* __restrict__ t_od,
    const int* __restrict__ ptnp, const int* __restrict__ nptp,
    const int* __restrict__ nptnp,
    const float* __restrict__ w2, const float* __restrict__ b2,
    float* __restrict__ out) {
    const int tid = blockIdx.x * 256 + threadIdx.x;
    const int g = tid >> 4;        // edge id 0..3E-1
    const int lane = tid & 15;

    const __hip_bfloat16 *src_tbl, *dst_tbl;
    int si, di;
    if (g < NEDGE) {
        si = ptnp[g]; di = ptnp[NEDGE + g];
        src_tbl = t_ps; dst_tbl = t_od;
    } else if (g < 2 * NEDGE) {
        const int e = g - NEDGE;
        si = nptp[e]; di = nptp[NEDGE + e];
        src_tbl = t_os; dst_tbl = t_pd;
    } else {
        const int e = g - 2 * NEDGE;
        si = nptnp[e]; di = nptnp[NEDGE + e];
        src_tbl = t_os; dst_tbl = t_od;
    }

    const uint4 s4 = *(const uint4*)(src_tbl + (size_t)si * H + lane * 8);
    const uint4 d4 = *(const uint4*)(dst_tbl + (size_t)di * H + lane * 8);
    const float4 w2a = *(const float4*)(w2 + lane * 8);
    const float4 w2b = *(const float4*)(w2 + lane * 8 + 4);

    float s0, s1, d0, d1;
    float sum = 0.f;
    bf2_to_f(s4.x, s0, s1); bf2_to_f(d4.x, d0, d1);
    sum = fmaf(fmaxf(s0 + d0, 0.f), w2a.x, sum);
    sum = fmaf(fmaxf(s1 + d1, 0.f), w2a.y, sum);
    bf2_to_f(s4.y, s0, s1); bf2_to_f(d4.y, d0, d1);
    sum = fmaf(fmaxf(s0 + d0, 0.f), w2a.z, sum);
    sum = fmaf(fmaxf(s1 + d1, 0.f), w2a.w, sum);
    bf2_to_f(s4.z, s0, s1); bf2_to_f(d4.z, d0, d1);
    sum = fmaf(fmaxf(s0 + d0, 0.f), w2b.x, sum);
    sum = fmaf(fmaxf(s1 + d1, 0.f), w2b.y, sum);
    bf2_to_f(s4.w, s0, s1); bf2_to_f(d4.w, d0, d1);
    sum = fmaf(fmaxf(s0 + d0, 0.f), w2b.z, sum);
    sum = fmaf(fmaxf(s1 + d1, 0.f), w2b.w, sum);

    sum += __shfl_down(sum, 8, 16);
    sum += __shfl_down(sum, 4, 16);
    sum += __shfl_down(sum, 2, 16);
    sum += __shfl_down(sum, 1, 16);
    if (lane == 0) out[g] = sum + b2[0];
}

// Fallback (only if ws_size is too small): direct per-edge compute, fp32.
__global__ __launch_bounds__(128) void edge_direct(
    const float* __restrict__ zp, const float* __restrict__ zo,
    const int* __restrict__ ptnp, const int* __restrict__ nptp,
    const int* __restrict__ nptnp,
    const float* __restrict__ w1, const float* __restrict__ b1,
    const float* __restrict__ w2, const float* __restrict__ b2,
    float* __restrict__ out) {
    const int g = blockIdx.x;
    const int j = threadIdx.x;

    const float *src, *dst;
    int si, di;
    if (g < NEDGE) {
        si = ptnp[g]; di = ptnp[NEDGE + g]; src = zp; dst = zo;
    } else if (g < 2 * NEDGE) {
        const int e = g - NEDGE;
        si = nptp[e]; di = nptp[NEDGE + e]; src = zo; dst = zp;
    } else {
        const int e = g - 2 * NEDGE;
        si = nptnp[e]; di = nptnp[NEDGE + e]; src = zo; dst = zo;
    }
    const float* zs = src + si * H;
    const float* zd = dst + di * H;

    float acc = b1[j];
    for (int k = 0; k < H; ++k) acc = fmaf(zs[k], w1[k * H + j], acc);
    for (int k = 0; k < H; ++k) acc = fmaf(zd[k], w1[(H + k) * H + j], acc);
    float v = fmaxf(acc, 0.f) * w2[j];

    for (int off = 32; off > 0; off >>= 1) v += __shfl_down(v, off, 64);
    __shared__ float parts[2];
    if ((j & 63) == 0) parts[j >> 6] = v;
    __syncthreads();
    if (j == 0) out[g] = parts[0] + parts[1] + b2[0];
}

extern "C" void kernel_launch(void* const* d_in, const int* in_sizes, int n_in,
                              void* d_out, int out_size, void* d_ws, size_t ws_size,
                              hipStream_t stream) {
    const float* zp    = (const float*)d_in[0];
    const float* zo    = (const float*)d_in[1];
    const int*   ptnp  = (const int*)d_in[2];
    const int*   nptp  = (const int*)d_in[3];
    const int*   nptnp = (const int*)d_in[4];
    const float* w1    = (const float*)d_in[5];
    const float* b1    = (const float*)d_in[6];
    const float* w2    = (const float*)d_in[7];
    const float* b2    = (const float*)d_in[8];
    float* out = (float*)d_out;

    if (ws_size < WS_NEEDED) {
        edge_direct<<<3 * NEDGE, 128, 0, stream>>>(zp, zo, ptnp, nptp, nptnp,
                                                   w1, b1, w2, b2, out);
        return;
    }

    char* ws = (char*)d_ws;
    ushort* bsw = (ushort*)ws;
    ushort* t_ps = (ushort*)(ws + BSW_BYTES);
    ushort* t_pd = t_ps + TBL_ELEMS;
    ushort* t_os = t_pd + TBL_ELEMS;
    ushort* t_od = t_os + TBL_ELEMS;

    prep_bsw<<<128, 256, 0, stream>>>(w1, bsw);

    gemm_tables<<<GEMM_GRID, 256, 0, stream>>>(
        zp, zo, bsw, b1, t_ps, t_pd, t_os, t_od);

    const int total_threads = 3 * NEDGE * 16;
    edge_kernel<<<total_threads / 256, 256, 0, stream>>>(
        (const __hip_bfloat16*)t_ps, (const __hip_bfloat16*)t_pd,
        (const __hip_bfloat16*)t_os, (const __hip_bfloat16*)t_od,
        ptnp, nptp, nptnp, w2, b2, out);
}

// Round 7
// 254.918 us; speedup vs baseline: 1.7819x; 1.0437x over previous
//
#include <hip/hip_runtime.h>
#include <hip/hip_bf16.h>
#include <stdint.h>

#define H 128
#define NNODES 100000
#define NEDGE 500000
#define MT 32                  // node rows per GEMM tile (100000 = 3125*32 exact)
#define NT2 6250               // tiles across both z inputs (z-interleaved)
#define GEMM_GRID 768          // 3 blocks/CU (LDS-limited)
#define EPI_S 266              // ebuf stride in ushorts (256 + 10 pad)

// ws layout:
//   [0, 65536)        : Bsw  bf16, fragment-swizzled w1 (16 kb-groups x 256 cols x 8)
//   [65536, +25.6MB)x4: T_ps, T_pd, T_os, T_od  bf16 [100000][128]
#define BSW_BYTES 65536
#define TBL_ELEMS (NNODES * H)
#define WS_NEEDED ((size_t)BSW_BYTES + 4ULL * TBL_ELEMS * 2ULL)

typedef __bf16 bf16x8 __attribute__((ext_vector_type(8)));
typedef float f32x4 __attribute__((ext_vector_type(4)));

union frag_cast { uint4 u; bf16x8 b; ushort s[8]; };

__device__ __forceinline__ ushort f2bf(float f) {
    __hip_bfloat16 h = __float2bfloat16(f);
    return *(ushort*)&h;
}

__device__ __forceinline__ void bf2_to_f(uint32_t u, float& lo, float& hi) {
    union { uint32_t i; float f; } a, b;
    a.i = u << 16;
    b.i = u & 0xffff0000u;
    lo = a.f;
    hi = b.f;
}

// Build fragment-swizzled bf16 B from w1.
// Bsw element i: j=i&7, n=(i>>3)&255, kb=i>>11; k=kb*8+j;
// B[k][n] = (n<128) ? w1[k][n] : w1[128+k][n-128]
__global__ __launch_bounds__(256) void prep_bsw(const float* __restrict__ w1,
                                                ushort* __restrict__ bsw) {
    int i = blockIdx.x * 256 + threadIdx.x;  // 0..32767
    int j = i & 7;
    int n = (i >> 3) & 255;
    int kb = i >> 11;
    int k = kb * 8 + j;
    int r = (n < 128) ? k : (128 + k);
    int c = n & 127;
    bsw[i] = f2bf(w1[r * H + c]);
}

// Persistent GEMM, 256 thr = 4 waves, tile = [32 rows x 256 cols].
// A: global_load_lds dwordx4 into double-buffered LDS (XOR source swizzle);
// prefetch for tile t+1 hidden behind compute+epilogue (2 barriers/tile).
// Epilogue staged through padded LDS so global stores are full-line uint4.
__global__ __launch_bounds__(256, 3) void gemm_tables(
    const float* __restrict__ zp, const float* __restrict__ zo,
    const ushort* __restrict__ bsw, const float* __restrict__ b1,
    ushort* __restrict__ t_ps, ushort* __restrict__ t_pd,
    ushort* __restrict__ t_os, ushort* __restrict__ t_od) {
    __shared__ float abuf[2][MT * H];     // 2 x 16 KB A staging
    __shared__ ushort ebuf[MT * EPI_S];   // 17 KB epilogue staging

    const int t = threadIdx.x;
    const int wave = t >> 6;
    const int lane = t & 63;
    const int l15 = lane & 15;
    const int quad = lane >> 4;
    const int n0 = wave * 64;            // wave's output col base (0..255)
    const int half = wave >> 1;          // 0: s-cols, 1: d-cols

    // ---- Per-block constants: B fragments (16 x 16B, L2-hot) + bias ----
    frag_cast bfr[4][4];
#pragma unroll
    for (int s = 0; s < 4; ++s)
#pragma unroll
        for (int nt = 0; nt < 4; ++nt)
            bfr[s][nt].u = *(const uint4*)(bsw + ((s * 4 + quad) * 256 + n0 + nt * 16 + l15) * 8);

    float bias[4] = {0.f, 0.f, 0.f, 0.f};
    if (half) {
#pragma unroll
        for (int nt = 0; nt < 4; ++nt)
            bias[nt] = b1[(n0 - 128) + nt * 16 + l15];
    }

    // Staging offsets (constant across tiles):
    int src_off[4], lds_off[4];
#pragma unroll
    for (int i = 0; i < 4; ++i) {
        const int r = (wave * 4 + i) * 2 + (lane >> 5);
        const int jsrc = (lane & 31) ^ (r & 15);
        src_off[i] = r * H + jsrc * 4;      // floats
        lds_off[i] = (wave * 4 + i) * 256;  // floats
    }

    // ---- Prologue: DMA first tile into buf 0 ----
    int tile = blockIdx.x;
    if (tile < NT2) {
        const float* zt = ((tile & 1) ? zo : zp) + (size_t)((tile >> 1) * MT) * H;
#pragma unroll
        for (int i = 0; i < 4; ++i)
            __builtin_amdgcn_global_load_lds(
                (const __attribute__((address_space(1))) uint32_t*)(zt + src_off[i]),
                (__attribute__((address_space(3))) uint32_t*)(&abuf[0][0] + lds_off[i]),
                16, 0, 0);
    }

    int buf = 0;
    for (; tile < NT2; tile += GEMM_GRID) {
        __syncthreads();  // B_top: drains DMA(tile); also fences ebuf reuse

        // ---- Prefetch DMA for next tile into the other buffer ----
        const int nxt = tile + GEMM_GRID;
        if (nxt < NT2) {
            const float* zt = ((nxt & 1) ? zo : zp) + (size_t)((nxt >> 1) * MT) * H;
#pragma unroll
            for (int i = 0; i < 4; ++i)
                __builtin_amdgcn_global_load_lds(
                    (const __attribute__((address_space(1))) uint32_t*)(zt + src_off[i]),
                    (__attribute__((address_space(3))) uint32_t*)(&abuf[buf ^ 1][0] + lds_off[i]),
                    16, 0, 0);
        }

        // ---- Compute: rows 0..31 (2 mt), wave cols n0..n0+63 (4 nt), K=128 ----
        const float* __restrict__ ab = &abuf[buf][0];
        f32x4 acc[2][4];
#pragma unroll
        for (int mt = 0; mt < 2; ++mt)
#pragma unroll
            for (int nt = 0; nt < 4; ++nt)
                acc[mt][nt] = (f32x4){0.f, 0.f, 0.f, 0.f};

#pragma unroll
        for (int s = 0; s < 4; ++s)
#pragma unroll
            for (int mt = 0; mt < 2; ++mt) {
                const int row = mt * 16 + l15;
                const int c = s * 4 + quad;  // 32B chunk -> b128 units 2c, 2c+1
                const float4 vlo = *(const float4*)(ab + row * H + ((2 * c) ^ l15) * 4);
                const float4 vhi = *(const float4*)(ab + row * H + ((2 * c + 1) ^ l15) * 4);
                frag_cast a;
                a.s[0] = f2bf(vlo.x); a.s[1] = f2bf(vlo.y);
                a.s[2] = f2bf(vlo.z); a.s[3] = f2bf(vlo.w);
                a.s[4] = f2bf(vhi.x); a.s[5] = f2bf(vhi.y);
                a.s[6] = f2bf(vhi.z); a.s[7] = f2bf(vhi.w);
#pragma unroll
                for (int nt = 0; nt < 4; ++nt)
                    acc[mt][nt] = __builtin_amdgcn_mfma_f32_16x16x32_bf16(
                        a.b, bfr[s][nt].b, acc[mt][nt], 0, 0, 0);
            }

        // ---- Epilogue stage: acc -> ebuf (D: col=l15, row=quad*4+reg) ----
#pragma unroll
        for (int mt = 0; mt < 2; ++mt)
#pragma unroll
            for (int nt = 0; nt < 4; ++nt) {
                const int col = n0 + nt * 16 + l15;
#pragma unroll
                for (int r = 0; r < 4; ++r)
                    ebuf[(mt * 16 + quad * 4 + r) * EPI_S + col] =
                        f2bf(acc[mt][nt][r] + bias[nt]);
            }

        __syncthreads();  // B_mid: ebuf ready (DMA covered by compute+epi)

        // ---- Coalesced stores: 1024 chunks of 16B; wave writes 4 KB contig ----
        const int zsel = tile & 1;
        const int node0 = (tile >> 1) * MT;
        ushort* __restrict__ stab = zsel ? t_os : t_ps;
        ushort* __restrict__ dtab = zsel ? t_od : t_pd;
#pragma unroll
        for (int i = 0; i < 4; ++i) {
            const int c = i * 256 + t;        // 0..1023
            const int table = c >> 9;         // 0: s-table, 1: d-table
            const int row = (c >> 4) & 31;
            const int ch = c & 15;            // 16B chunk within row
            ushort* __restrict__ dst = table ? dtab : stab;
            *(uint4*)(dst + (size_t)(node0 + row) * H + ch * 8) =
                *(const uint4*)(ebuf + row * EPI_S + table * 128 + ch * 8);
        }

        buf ^= 1;
    }
}

// 16 lanes per group; each group handles 4 consecutive edges (4x MLP:
// 32 outstanding 256-B gathers per wave instead of 8). Each lane covers
// 8 channels via 16B bf16 loads. Correctness verified in round 5.
__global__ __launch_bounds__(256) void edge_kernel(
    const __hip_bfloat16* __restrict__ t_ps, const __hip_bfloat16* __restrict__ t_pd,
    const __hip_bfloat16* __restrict__ t_os, const __hip_bfloat16* __restrict__ t_od,
    const int* __restrict__ ptnp, const int* __restrict__ nptp,
    const int* __restrict__ nptnp,
    const float* __restrict__ w2, const float* __restrict__ b2,
    float* __restrict__ out) {
    const int tid = blockIdx.x * 256 + threadIdx.x;
    const int gg = tid >> 4;       // group id, 0..374999
    if (gg >= (3 * NEDGE) / 4) return;
    const int lane = tid & 15;
    const int e0 = gg * 4;         // 4 edges, never straddle a type boundary

    const __hip_bfloat16 *src_tbl, *dst_tbl;
    const int* idx;
    int ebase;
    if (e0 < NEDGE) {
        idx = ptnp; ebase = e0;
        src_tbl = t_ps; dst_tbl = t_od;
    } else if (e0 < 2 * NEDGE) {
        idx = nptp; ebase = e0 - NEDGE;
        src_tbl = t_os; dst_tbl = t_pd;
    } else {
        idx = nptnp; ebase = e0 - 2 * NEDGE;
        src_tbl = t_os; dst_tbl = t_od;
    }

    const int4 si = *(const int4*)(idx + ebase);
    const int4 di = *(const int4*)(idx + NEDGE + ebase);

    // Issue all 8 gathers up front (independent -> 8 in flight per lane).
    const uint4 s0 = *(const uint4*)(src_tbl + (size_t)si.x * H + lane * 8);
    const uint4 d0 = *(const uint4*)(dst_tbl + (size_t)di.x * H + lane * 8);
    const uint4 s1 = *(const uint4*)(src_tbl + (size_t)si.y * H + lane * 8);
    const uint4 d1 = *(const uint4*)(dst_tbl + (size_t)di.y * H + lane * 8);
    const uint4 s2 = *(const uint4*)(src_tbl + (size_t)si.z * H + lane * 8);
    const uint4 d2 = *(const uint4*)(dst_tbl + (size_t)di.z * H + lane * 8);
    const uint4 s3 = *(const uint4*)(src_tbl + (size_t)si.w * H + lane * 8);
    const uint4 d3 = *(const uint4*)(dst_tbl + (size_t)di.w * H + lane * 8);

    const float4 w2a = *(const float4*)(w2 + lane * 8);
    const float4 w2b = *(const float4*)(w2 + lane * 8 + 4);
    const float wv[8] = {w2a.x, w2a.y, w2a.z, w2a.w, w2b.x, w2b.y, w2b.z, w2b.w};

    float sum[4] = {0.f, 0.f, 0.f, 0.f};
    const uint4* sv[4] = {&s0, &s1, &s2, &s3};
    const uint4* dv[4] = {&d0, &d1, &d2, &d3};
#pragma unroll
    for (int e = 0; e < 4; ++e) {
        const uint32_t* su = (const uint32_t*)sv[e];
        const uint32_t* du = (const uint32_t*)dv[e];
        float acc = 0.f;
#pragma unroll
        for (int q = 0; q < 4; ++q) {
            float a0, a1, b0, b1v;
            bf2_to_f(su[q], a0, a1);
            bf2_to_f(du[q], b0, b1v);
            acc = fmaf(fmaxf(a0 + b0, 0.f), wv[2 * q], acc);
            acc = fmaf(fmaxf(a1 + b1v, 0.f), wv[2 * q + 1], acc);
        }
        sum[e] = acc;
    }

#pragma unroll
    for (int e = 0; e < 4; ++e) {
        sum[e] += __shfl_down(sum[e], 8, 16);
        sum[e] += __shfl_down(sum[e], 4, 16);
        sum[e] += __shfl_down(sum[e], 2, 16);
        sum[e] += __shfl_down(sum[e], 1, 16);
    }
    if (lane == 0) {
        const float bb = b2[0];
        float4 o = {sum[0] + bb, sum[1] + bb, sum[2] + bb, sum[3] + bb};
        *(float4*)(out + e0) = o;
    }
}

// Fallback (only if ws_size is too small): direct per-edge compute, fp32.
__global__ __launch_bounds__(128) void edge_direct(
    const float* __restrict__ zp, const float* __restrict__ zo,
    const int* __restrict__ ptnp, const int* __restrict__ nptp,
    const int* __restrict__ nptnp,
    const float* __restrict__ w1, const float* __restrict__ b1,
    const float* __restrict__ w2, const float* __restrict__ b2,
    float* __restrict__ out) {
    const int g = blockIdx.x;
    const int j = threadIdx.x;

    const float *src, *dst;
    int si, di;
    if (g < NEDGE) {
        si = ptnp[g]; di = ptnp[NEDGE + g]; src = zp; dst = zo;
    } else if (g < 2 * NEDGE) {
        const int e = g - NEDGE;
        si = nptp[e]; di = nptp[NEDGE + e]; src = zo; dst = zp;
    } else {
        const int e = g - 2 * NEDGE;
        si = nptnp[e]; di = nptnp[NEDGE + e]; src = zo; dst = zo;
    }
    const float* zs = src + si * H;
    const float* zd = dst + di * H;

    float acc = b1[j];
    for (int k = 0; k < H; ++k) acc = fmaf(zs[k], w1[k * H + j], acc);
    for (int k = 0; k < H; ++k) acc = fmaf(zd[k], w1[(H + k) * H + j], acc);
    float v = fmaxf(acc, 0.f) * w2[j];

    for (int off = 32; off > 0; off >>= 1) v += __shfl_down(v, off, 64);
    __shared__ float parts[2];
    if ((j & 63) == 0) parts[j >> 6] = v;
    __syncthreads();
    if (j == 0) out[g] = parts[0] + parts[1] + b2[0];
}

extern "C" void kernel_launch(void* const* d_in, const int* in_sizes, int n_in,
                              void* d_out, int out_size, void* d_ws, size_t ws_size,
                              hipStream_t stream) {
    const float* zp    = (const float*)d_in[0];
    const float* zo    = (const float*)d_in[1];
    const int*   ptnp  = (const int*)d_in[2];
    const int*   nptp  = (const int*)d_in[3];
    const int*   nptnp = (const int*)d_in[4];
    const float* w1    = (const float*)d_in[5];
    const float* b1    = (const float*)d_in[6];
    const float* w2    = (const float*)d_in[7];
    const float* b2    = (const float*)d_in[8];
    float* out = (float*)d_out;

    if (ws_size < WS_NEEDED) {
        edge_direct<<<3 * NEDGE, 128, 0, stream>>>(zp, zo, ptnp, nptp, nptnp,
                                                   w1, b1, w2, b2, out);
        return;
    }

    char* ws = (char*)d_ws;
    ushort* bsw = (ushort*)ws;
    ushort* t_ps = (ushort*)(ws + BSW_BYTES);
    ushort* t_pd = t_ps + TBL_ELEMS;
    ushort* t_os = t_pd + TBL_ELEMS;
    ushort* t_od = t_os + TBL_ELEMS;

    prep_bsw<<<128, 256, 0, stream>>>(w1, bsw);

    gemm_tables<<<GEMM_GRID, 256, 0, stream>>>(
        zp, zo, bsw, b1, t_ps, t_pd, t_os, t_od);

    const int ngroups = (3 * NEDGE) / 4;                 // 375000
    const int nblocks = (ngroups * 16 + 255) / 256;      // 23438
    edge_kernel<<<nblocks, 256, 0, stream>>>(
        (const __hip_bfloat16*)t_ps, (const __hip_bfloat16*)t_pd,
        (const __hip_bfloat16*)t_os, (const __hip_bfloat16*)t_od,
        ptnp, nptp, nptnp, w2, b2, out);
}